// Round 2
// baseline (744.884 us; speedup 1.0000x reference)
//
#include <hip/hip_runtime.h>

typedef __bf16 bf16x8 __attribute__((ext_vector_type(8)));
typedef __bf16 bf16x4 __attribute__((ext_vector_type(4)));
typedef float f32x4 __attribute__((ext_vector_type(4)));

#define SCALE 0.17677669529663687f  // 1/sqrt(32)

// ================= shared GEMM body: C[M,256] = A[M,256] @ Wt + bias =========
// MODE 0: C bf16 natural [M][256]
// MODE 1: C bf16 transposed-per-batch vT[(b*256+n)*1024 + tloc]  (M = 4096)
// MODE 2: C fp32 [M][256] + resid
template<int MODE>
__device__ __forceinline__ void gemm_body(const __bf16* __restrict__ A,
    const __bf16* __restrict__ Wt, const float* __restrict__ bias,
    const float* __restrict__ resid, void* __restrict__ Cout,
    int bx, int by, int tid) {
  const int w = tid >> 6, l = tid & 63;
  const int col = l & 15, quad = l >> 4;
  const int row0 = bx * 64 + w * 16;
  const int col0 = by * 64;
  f32x4 acc[4] = {{0.f,0.f,0.f,0.f},{0.f,0.f,0.f,0.f},{0.f,0.f,0.f,0.f},{0.f,0.f,0.f,0.f}};
  const __bf16* ap = A + (size_t)(row0 + col) * 256 + quad * 8;
  #pragma unroll
  for (int ks = 0; ks < 8; ++ks) {
    bf16x8 af = *(const bf16x8*)(ap + ks * 32);
    #pragma unroll
    for (int n = 0; n < 4; ++n) {
      bf16x8 bf = *(const bf16x8*)(Wt + (size_t)(col0 + n * 16 + col) * 256 + ks * 32 + quad * 8);
      acc[n] = __builtin_amdgcn_mfma_f32_16x16x32_bf16(af, bf, acc[n], 0, 0, 0);
    }
  }
  const int rbase = row0 + quad * 4;
  #pragma unroll
  for (int n = 0; n < 4; ++n) {
    const int cc = col0 + n * 16 + col;
    const float bv = bias ? bias[cc] : 0.0f;
    if (MODE == 0) {
      __bf16* C = (__bf16*)Cout;
      #pragma unroll
      for (int r = 0; r < 4; ++r)
        C[(size_t)(rbase + r) * 256 + cc] = (__bf16)(acc[n][r] + bv);
    } else if (MODE == 1) {
      __bf16* C = (__bf16*)Cout;
      const int bb2 = rbase >> 10, tl = rbase & 1023;
      bf16x4 o4;
      #pragma unroll
      for (int r = 0; r < 4; ++r) o4[r] = (__bf16)(acc[n][r] + bv);
      *(bf16x4*)(C + ((size_t)(bb2 * 256 + cc)) * 1024 + tl) = o4;
    } else {
      float* C = (float*)Cout;
      #pragma unroll
      for (int r = 0; r < 4; ++r) {
        size_t off = (size_t)(rbase + r) * 256 + cc;
        C[off] = acc[n][r] + bv + resid[off];
      }
    }
  }
}

// ================= L1 "prep": castw (5 weights) + LN1 + pool =================
// blocks [0,1280): weight cast+transpose; [1280,5376): LN1; [5376,6400): pool
__global__ __launch_bounds__(256) void prep_kernel(
    const float* __restrict__ W0, const float* __restrict__ W1,
    const float* __restrict__ W2, const float* __restrict__ W3,
    const float* __restrict__ W4,
    __bf16* __restrict__ T0, __bf16* __restrict__ T1,
    __bf16* __restrict__ T2, __bf16* __restrict__ T3,
    __bf16* __restrict__ T4,
    const float* __restrict__ x, const float* __restrict__ g1,
    const float* __restrict__ b1, __bf16* __restrict__ xn,
    __bf16* __restrict__ xp) {
  const int blk = blockIdx.x, tid = threadIdx.x;
  if (blk < 1280) {
    int which = blk >> 8;
    const float* W = which == 0 ? W0 : which == 1 ? W1 : which == 2 ? W2 : which == 3 ? W3 : W4;
    __bf16* T = which == 0 ? T0 : which == 1 ? T1 : which == 2 ? T2 : which == 3 ? T3 : T4;
    int id = (blk & 255) * 256 + tid;
    int kk = id >> 8, n = id & 255;
    T[n * 256 + kk] = (__bf16)W[id];
  } else if (blk < 5376) {
    int wid = ((blk - 1280) * 256 + tid) >> 6;
    int lane = tid & 63;
    const float4 v = *(const float4*)(x + (size_t)wid * 256 + lane * 4);
    float s = v.x + v.y + v.z + v.w;
    #pragma unroll
    for (int off = 32; off; off >>= 1) s += __shfl_down(s, off);
    float mean = __shfl(s, 0) * (1.0f / 256.0f);
    float dx = v.x - mean, dy = v.y - mean, dz = v.z - mean, dw = v.w - mean;
    float vs = dx * dx + dy * dy + dz * dz + dw * dw;
    #pragma unroll
    for (int off = 32; off; off >>= 1) vs += __shfl_down(vs, off);
    float rstd = rsqrtf(__shfl(vs, 0) * (1.0f / 256.0f) + 1e-5f);
    const float4 gg = *(const float4*)(g1 + lane * 4);
    const float4 bv = *(const float4*)(b1 + lane * 4);
    bf16x4 o4;
    o4[0] = (__bf16)(dx * rstd * gg.x + bv.x);
    o4[1] = (__bf16)(dy * rstd * gg.y + bv.y);
    o4[2] = (__bf16)(dz * rstd * gg.z + bv.z);
    o4[3] = (__bf16)(dw * rstd * gg.w + bv.w);
    *(bf16x4*)(xn + (size_t)wid * 256 + lane * 4) = o4;
  } else {
    int idx = (blk - 5376) * 256 + tid;   // 1024*256 ids
    int t = idx >> 6, c4 = (idx & 63) << 2;
    int b = t >> 10, rem = t & 1023;
    int i = rem >> 5, j = rem & 31;
    size_t base = ((size_t)b * 4096 + i * 128 + j * 2) * 256 + c4;
    float4 a0 = *(const float4*)(x + base);
    float4 a1 = *(const float4*)(x + base + 256);
    float4 a2 = *(const float4*)(x + base + 16384);
    float4 a3 = *(const float4*)(x + base + 16640);
    bf16x4 o4;
    o4[0] = (__bf16)(0.25f * (a0.x + a1.x + a2.x + a3.x));
    o4[1] = (__bf16)(0.25f * (a0.y + a1.y + a2.y + a3.y));
    o4[2] = (__bf16)(0.25f * (a0.z + a1.z + a2.z + a3.z));
    o4[3] = (__bf16)(0.25f * (a0.w + a1.w + a2.w + a3.w));
    *(bf16x4*)(xp + (size_t)t * 256 + c4) = o4;
  }
}

// ================= L2 "qm": Q-GEMM + (mean-GEMM fused with LN2) ==============
// blocks [0,1024): Q-GEMM mode0. blocks [1024,1088): mean-GEMM, each wave owns
// 16 FULL rows (16 n-tiles) -> row LN stats via in-register + __shfl_xor within
// the 16-lane col group; writes xr directly (fp32 LN, closer to reference than
// the old bf16-roundtrip ln2).
__global__ __launch_bounds__(256) void qm_kernel(
    const __bf16* __restrict__ xn, const __bf16* __restrict__ WtQ,
    const float* __restrict__ bq, __bf16* __restrict__ qb,
    const __bf16* __restrict__ xp, const __bf16* __restrict__ WtM,
    const float* __restrict__ g2, const float* __restrict__ b2,
    __bf16* __restrict__ xr) {
  const int blk = blockIdx.x, tid = threadIdx.x;
  if (blk < 1024) {
    gemm_body<0>(xn, WtQ, bq, nullptr, qb, blk & 255, blk >> 8, tid);
    return;
  }
  const int w = tid >> 6, l = tid & 63;
  const int col = l & 15, quad = l >> 4;
  const int row0 = (blk - 1024) * 64 + w * 16;
  f32x4 acc[16];
  #pragma unroll
  for (int n = 0; n < 16; ++n) acc[n] = (f32x4){0.f, 0.f, 0.f, 0.f};
  const __bf16* ap = xp + (size_t)(row0 + col) * 256 + quad * 8;
  #pragma unroll
  for (int ks = 0; ks < 8; ++ks) {
    bf16x8 af = *(const bf16x8*)(ap + ks * 32);
    #pragma unroll
    for (int n = 0; n < 16; ++n) {
      bf16x8 bf = *(const bf16x8*)(WtM + (size_t)(n * 16 + col) * 256 + ks * 32 + quad * 8);
      acc[n] = __builtin_amdgcn_mfma_f32_16x16x32_bf16(af, bf, acc[n], 0, 0, 0);
    }
  }
  // LN over each output row (256 cols = 16 lanes x 16 n-tiles)
  #pragma unroll
  for (int r = 0; r < 4; ++r) {
    float s = 0.f;
    #pragma unroll
    for (int n = 0; n < 16; ++n) s += acc[n][r];
    #pragma unroll
    for (int m = 1; m < 16; m <<= 1) s += __shfl_xor(s, m);
    float mean = s * (1.0f / 256.0f);
    float vs = 0.f;
    #pragma unroll
    for (int n = 0; n < 16; ++n) { float d = acc[n][r] - mean; vs += d * d; }
    #pragma unroll
    for (int m = 1; m < 16; m <<= 1) vs += __shfl_xor(vs, m);
    float rstd = rsqrtf(vs * (1.0f / 256.0f) + 1e-5f);
    int row = row0 + quad * 4 + r;
    #pragma unroll
    for (int n = 0; n < 16; ++n) {
      int cc = n * 16 + col;
      xr[(size_t)row * 256 + cc] = (__bf16)((acc[n][r] - mean) * rstd * g2[cc] + b2[cc]);
    }
  }
}

// ================= L3 "kv": K-GEMM (mode0) + V-GEMM (mode1) ==================
__global__ __launch_bounds__(256) void kv_kernel(
    const __bf16* __restrict__ xr, const __bf16* __restrict__ WtK,
    const float* __restrict__ bk, __bf16* __restrict__ kbuf,
    const __bf16* __restrict__ WtV, const float* __restrict__ bv,
    __bf16* __restrict__ vTb) {
  const int blk = blockIdx.x, tid = threadIdx.x;
  if (blk < 256) gemm_body<0>(xr, WtK, bk, nullptr, kbuf, blk & 63, blk >> 6, tid);
  else { int k = blk - 256; gemm_body<1>(xr, WtV, bv, nullptr, vTb, k & 63, k >> 6, tid); }
}

// ================= L5 "o": O-GEMM mode2 (bias + resid, fp32 out) =============
__global__ __launch_bounds__(256) void o_kernel(
    const __bf16* __restrict__ oat, const __bf16* __restrict__ WtO,
    const float* __restrict__ bo, const float* __restrict__ resid,
    float* __restrict__ out) {
  gemm_body<2>(oat, WtO, bo, resid, out, blockIdx.x, blockIdx.y, threadIdx.x);
}

// ================= L4 fused attention =======================================
// QK^T -> softmax -> attn store (EARLY, nontemporal, drains under PV) -> PV.
// Swizzle c ^ ((row&7)<<2): phase-2 b128 row reads conflict-free; phase-3 b128
// A-frag reads uniform over 8 bank-groups.
__device__ __forceinline__ int swz(int row, int c) {
  return row * 1024 + (c ^ ((row & 7) << 2));
}

__global__ __launch_bounds__(256) void attn_fused(
    const __bf16* __restrict__ q, const __bf16* __restrict__ kb,
    const __bf16* __restrict__ vT, float* __restrict__ attn,
    __bf16* __restrict__ oat) {
  __shared__ float Ss[16 * 1024];     // 64 KiB: scores then UNNORMALIZED exp
  __shared__ float part[64 * 32];     //  8 KiB: cross-wave PV reduce
  __shared__ float inv_s[16];         // per-row 1/sum
  const int tid = threadIdx.x;
  const int w = tid >> 6, l = tid & 63;
  const int col = l & 15, quad = l >> 4;
  const int bh = blockIdx.y, b = bh >> 3, h = bh & 7;
  const int q0 = blockIdx.x * 16;

  // Phase 1: S = SCALE * Q K^T for this wave's 256-col strip
  bf16x8 qf = *(const bf16x8*)(q + ((size_t)(b * 4096 + q0 + col)) * 256 + h * 32 + quad * 8);
  const __bf16* kbase = kb + ((size_t)(b * 1024 + col)) * 256 + h * 32 + quad * 8;
  #pragma unroll 4
  for (int t = 0; t < 16; ++t) {
    int j0 = w * 256 + t * 16;
    bf16x8 kf = *(const bf16x8*)(kbase + (size_t)j0 * 256);
    f32x4 c = {0.f, 0.f, 0.f, 0.f};
    c = __builtin_amdgcn_mfma_f32_16x16x32_bf16(qf, kf, c, 0, 0, 0);
    #pragma unroll
    for (int r = 0; r < 4; ++r)
      Ss[swz(quad * 4 + r, j0 + col)] = c[r] * SCALE;
  }
  __syncthreads();

  // Phase 2: softmax stats; write back UNNORMALIZED exp; no global stores.
  #pragma unroll
  for (int rr = 0; rr < 4; ++rr) {
    int row = w * 4 + rr;
    float4 v4[4];
    float m = -1e30f;
    #pragma unroll
    for (int i = 0; i < 4; ++i) {
      v4[i] = *(const float4*)(&Ss[swz(row, i * 256 + l * 4)]);
      m = fmaxf(m, fmaxf(fmaxf(v4[i].x, v4[i].y), fmaxf(v4[i].z, v4[i].w)));
    }
    #pragma unroll
    for (int off = 32; off; off >>= 1) m = fmaxf(m, __shfl_down(m, off));
    m = __shfl(m, 0);
    float s = 0.f;
    #pragma unroll
    for (int i = 0; i < 4; ++i) {
      v4[i].x = __expf(v4[i].x - m); v4[i].y = __expf(v4[i].y - m);
      v4[i].z = __expf(v4[i].z - m); v4[i].w = __expf(v4[i].w - m);
      s += v4[i].x + v4[i].y + v4[i].z + v4[i].w;
    }
    #pragma unroll
    for (int off = 32; off; off >>= 1) s += __shfl_down(s, off);
    if (l == 0) inv_s[row] = 1.0f / __shfl(s, 0);
    #pragma unroll
    for (int i = 0; i < 4; ++i)
      *(float4*)(&Ss[swz(row, i * 256 + l * 4)]) = v4[i];
  }
  __syncthreads();

  // EARLY attn store: inputs (Ss unnorm exp + inv_s) are final here. Fire the
  // nontemporal stores now so the 64 KiB/block HBM burst drains UNDER the PV
  // MFMAs and the reduce, instead of serializing at kernel end.
  {
    float* abase = attn + ((size_t)bh * 4096 + q0) * 1024;
    int c4 = tid * 4;
    #pragma unroll 4
    for (int row = 0; row < 16; ++row) {
      f32x4 pv = *(const f32x4*)(&Ss[swz(row, c4)]);
      float iv = inv_s[row];
      pv[0] *= iv; pv[1] *= iv; pv[2] *= iv; pv[3] *= iv;
      __builtin_nontemporal_store(pv, (f32x4*)(abase + (size_t)row * 1024 + c4));
    }
  }

  // Phase 3: partial PV over this wave's 256-col strip (unnormalized probs;
  // 1/sum folded into the reduce epilogue).
  f32x4 a0 = {0.f, 0.f, 0.f, 0.f}, a1 = {0.f, 0.f, 0.f, 0.f};
  const __bf16* v0p = vT + ((size_t)(b * 256 + h * 32 + col)) * 1024;
  const __bf16* v1p = v0p + 16 * 1024;
  #pragma unroll 2
  for (int s8 = 0; s8 < 8; ++s8) {
    int k0 = w * 256 + s8 * 32;
    int c0 = k0 + quad * 8;
    f32x4 p0 = *(const f32x4*)(&Ss[swz(col, c0)]);
    f32x4 p1 = *(const f32x4*)(&Ss[swz(col, c0 + 4)]);
    bf16x8 af;
    af[0] = (__bf16)p0[0]; af[1] = (__bf16)p0[1]; af[2] = (__bf16)p0[2]; af[3] = (__bf16)p0[3];
    af[4] = (__bf16)p1[0]; af[5] = (__bf16)p1[1]; af[6] = (__bf16)p1[2]; af[7] = (__bf16)p1[3];
    bf16x8 b0 = *(const bf16x8*)(v0p + k0 + quad * 8);
    bf16x8 b1 = *(const bf16x8*)(v1p + k0 + quad * 8);
    a0 = __builtin_amdgcn_mfma_f32_16x16x32_bf16(af, b0, a0, 0, 0, 0);
    a1 = __builtin_amdgcn_mfma_f32_16x16x32_bf16(af, b1, a1, 0, 0, 0);
  }

  // cross-wave reduce via separate part buffer
  #pragma unroll
  for (int r = 0; r < 4; ++r) {
    part[(w * 16 + quad * 4 + r) * 32 + col] = a0[r];
    part[(w * 16 + quad * 4 + r) * 32 + 16 + col] = a1[r];
  }
  __syncthreads();
  int idx = tid;
  #pragma unroll
  for (int it = 0; it < 2; ++it, idx += 256) {
    int row = idx >> 5, d = idx & 31;
    float sum = (part[row * 32 + d] + part[(16 + row) * 32 + d]
               + part[(32 + row) * 32 + d] + part[(48 + row) * 32 + d]) * inv_s[row];
    oat[((size_t)(b * 4096 + q0 + row)) * 256 + h * 32 + d] = (__bf16)sum;
  }
}

extern "C" void kernel_launch(void* const* d_in, const int* in_sizes, int n_in,
                              void* d_out, int out_size, void* d_ws, size_t ws_size,
                              hipStream_t stream) {
  (void)in_sizes; (void)n_in; (void)out_size; (void)ws_size;
  const float* x     = (const float*)d_in[0];
  const float* ln1_g = (const float*)d_in[2];
  const float* ln1_b = (const float*)d_in[3];
  const float* Wq    = (const float*)d_in[4];
  const float* bq    = (const float*)d_in[5];
  const float* Wk    = (const float*)d_in[6];
  const float* bk    = (const float*)d_in[7];
  const float* Wv    = (const float*)d_in[8];
  const float* bv    = (const float*)d_in[9];
  const float* Wmean = (const float*)d_in[10];
  const float* ln2_g = (const float*)d_in[11];
  const float* ln2_b = (const float*)d_in[12];
  const float* Wo    = (const float*)d_in[13];
  const float* bo    = (const float*)d_in[14];

  float* out  = (float*)d_out;           // [16384, 256] fp32
  float* attn = out + 4194304;           // [32, 4096, 1024] fp32

  __bf16* w0   = (__bf16*)d_ws;
  __bf16* xn   = w0;                     // 4,194,304
  __bf16* qb   = w0 + 4194304;           // 4,194,304
  __bf16* oat  = w0 + 8388608;           // 4,194,304
  __bf16* xp   = w0 + 12582912;          // 1,048,576
  __bf16* xr   = w0 + 14680064;          // 1,048,576
  __bf16* kbuf = w0 + 15728640;          // 1,048,576
  __bf16* vTb  = w0 + 16777216;          // 1,048,576
  __bf16* WtQ  = w0 + 17825792;          // 5 x 65,536
  __bf16* WtK  = WtQ + 65536;
  __bf16* WtV  = WtK + 65536;
  __bf16* WtM  = WtV + 65536;
  __bf16* WtO  = WtM + 65536;

  // L1: castw(1280) + LN1(4096) + pool(1024) = 6400 blocks
  prep_kernel<<<6400, 256, 0, stream>>>(Wq, Wk, Wv, Wmean, Wo,
                                        WtQ, WtK, WtV, WtM, WtO,
                                        x, ln1_g, ln1_b, xn, xp);
  // L2: Q-GEMM(1024) + meanGEMM+LN2(64) = 1088 blocks
  qm_kernel<<<1088, 256, 0, stream>>>(xn, WtQ, bq, qb, xp, WtM, ln2_g, ln2_b, xr);
  // L3: K-GEMM(256) + V-GEMM(256) = 512 blocks
  kv_kernel<<<512, 256, 0, stream>>>(xr, WtK, bk, kbuf, WtV, bv, vTb);
  // L4: fused attention
  attn_fused<<<dim3(256, 32), 256, 0, stream>>>(qb, kbuf, vTb, attn, oat);
  // L5: O-GEMM + bias + residual
  o_kernel<<<dim3(256, 4), 256, 0, stream>>>(oat, WtO, bo, x, out);
}

// Round 3
// 716.100 us; speedup vs baseline: 1.0402x; 1.0402x over previous
//
#include <hip/hip_runtime.h>

typedef __bf16 bf16x8 __attribute__((ext_vector_type(8)));
typedef __bf16 bf16x4 __attribute__((ext_vector_type(4)));
typedef float f32x4 __attribute__((ext_vector_type(4)));

#define SCALE 0.17677669529663687f  // 1/sqrt(32)

// ================= shared GEMM body: C[M,256] = A[M,256] @ Wt + bias =========
// MODE 0: C bf16 natural [M][256]
// MODE 1: C bf16 transposed-per-batch vT[(b*256+n)*1024 + tloc]  (M = 4096)
template<int MODE>
__device__ __forceinline__ void gemm_body(const __bf16* __restrict__ A,
    const __bf16* __restrict__ Wt, const float* __restrict__ bias,
    void* __restrict__ Cout, int bx, int by, int tid) {
  const int w = tid >> 6, l = tid & 63;
  const int col = l & 15, quad = l >> 4;
  const int row0 = bx * 64 + w * 16;
  const int col0 = by * 64;
  f32x4 acc[4] = {{0.f,0.f,0.f,0.f},{0.f,0.f,0.f,0.f},{0.f,0.f,0.f,0.f},{0.f,0.f,0.f,0.f}};
  const __bf16* ap = A + (size_t)(row0 + col) * 256 + quad * 8;
  #pragma unroll
  for (int ks = 0; ks < 8; ++ks) {
    bf16x8 af = *(const bf16x8*)(ap + ks * 32);
    #pragma unroll
    for (int n = 0; n < 4; ++n) {
      bf16x8 bf = *(const bf16x8*)(Wt + (size_t)(col0 + n * 16 + col) * 256 + ks * 32 + quad * 8);
      acc[n] = __builtin_amdgcn_mfma_f32_16x16x32_bf16(af, bf, acc[n], 0, 0, 0);
    }
  }
  const int rbase = row0 + quad * 4;
  #pragma unroll
  for (int n = 0; n < 4; ++n) {
    const int cc = col0 + n * 16 + col;
    const float bv = bias ? bias[cc] : 0.0f;
    if (MODE == 0) {
      __bf16* C = (__bf16*)Cout;
      #pragma unroll
      for (int r = 0; r < 4; ++r)
        C[(size_t)(rbase + r) * 256 + cc] = (__bf16)(acc[n][r] + bv);
    } else {
      __bf16* C = (__bf16*)Cout;
      const int bb2 = rbase >> 10, tl = rbase & 1023;
      bf16x4 o4;
      #pragma unroll
      for (int r = 0; r < 4; ++r) o4[r] = (__bf16)(acc[n][r] + bv);
      *(bf16x4*)(C + ((size_t)(bb2 * 256 + cc)) * 1024 + tl) = o4;
    }
  }
}

// ================= L1 "prep": castw (5 weights) + LN1 + pool =================
__global__ __launch_bounds__(256) void prep_kernel(
    const float* __restrict__ W0, const float* __restrict__ W1,
    const float* __restrict__ W2, const float* __restrict__ W3,
    const float* __restrict__ W4,
    __bf16* __restrict__ T0, __bf16* __restrict__ T1,
    __bf16* __restrict__ T2, __bf16* __restrict__ T3,
    __bf16* __restrict__ T4,
    const float* __restrict__ x, const float* __restrict__ g1,
    const float* __restrict__ b1, __bf16* __restrict__ xn,
    __bf16* __restrict__ xp) {
  const int blk = blockIdx.x, tid = threadIdx.x;
  if (blk < 1280) {
    int which = blk >> 8;
    const float* W = which == 0 ? W0 : which == 1 ? W1 : which == 2 ? W2 : which == 3 ? W3 : W4;
    __bf16* T = which == 0 ? T0 : which == 1 ? T1 : which == 2 ? T2 : which == 3 ? T3 : T4;
    int id = (blk & 255) * 256 + tid;
    int kk = id >> 8, n = id & 255;
    T[n * 256 + kk] = (__bf16)W[id];
  } else if (blk < 5376) {
    int wid = ((blk - 1280) * 256 + tid) >> 6;
    int lane = tid & 63;
    const float4 v = *(const float4*)(x + (size_t)wid * 256 + lane * 4);
    float s = v.x + v.y + v.z + v.w;
    #pragma unroll
    for (int off = 32; off; off >>= 1) s += __shfl_down(s, off);
    float mean = __shfl(s, 0) * (1.0f / 256.0f);
    float dx = v.x - mean, dy = v.y - mean, dz = v.z - mean, dw = v.w - mean;
    float vs = dx * dx + dy * dy + dz * dz + dw * dw;
    #pragma unroll
    for (int off = 32; off; off >>= 1) vs += __shfl_down(vs, off);
    float rstd = rsqrtf(__shfl(vs, 0) * (1.0f / 256.0f) + 1e-5f);
    const float4 gg = *(const float4*)(g1 + lane * 4);
    const float4 bv = *(const float4*)(b1 + lane * 4);
    bf16x4 o4;
    o4[0] = (__bf16)(dx * rstd * gg.x + bv.x);
    o4[1] = (__bf16)(dy * rstd * gg.y + bv.y);
    o4[2] = (__bf16)(dz * rstd * gg.z + bv.z);
    o4[3] = (__bf16)(dw * rstd * gg.w + bv.w);
    *(bf16x4*)(xn + (size_t)wid * 256 + lane * 4) = o4;
  } else {
    int idx = (blk - 5376) * 256 + tid;   // 1024*256 ids
    int t = idx >> 6, c4 = (idx & 63) << 2;
    int b = t >> 10, rem = t & 1023;
    int i = rem >> 5, j = rem & 31;
    size_t base = ((size_t)b * 4096 + i * 128 + j * 2) * 256 + c4;
    float4 a0 = *(const float4*)(x + base);
    float4 a1 = *(const float4*)(x + base + 256);
    float4 a2 = *(const float4*)(x + base + 16384);
    float4 a3 = *(const float4*)(x + base + 16640);
    bf16x4 o4;
    o4[0] = (__bf16)(0.25f * (a0.x + a1.x + a2.x + a3.x));
    o4[1] = (__bf16)(0.25f * (a0.y + a1.y + a2.y + a3.y));
    o4[2] = (__bf16)(0.25f * (a0.z + a1.z + a2.z + a3.z));
    o4[3] = (__bf16)(0.25f * (a0.w + a1.w + a2.w + a3.w));
    *(bf16x4*)(xp + (size_t)t * 256 + c4) = o4;
  }
}

// ================= L2 "qm": Q-GEMM + (mean-GEMM fused with LN2) ==============
__global__ __launch_bounds__(256) void qm_kernel(
    const __bf16* __restrict__ xn, const __bf16* __restrict__ WtQ,
    const float* __restrict__ bq, __bf16* __restrict__ qb,
    const __bf16* __restrict__ xp, const __bf16* __restrict__ WtM,
    const float* __restrict__ g2, const float* __restrict__ b2,
    __bf16* __restrict__ xr) {
  const int blk = blockIdx.x, tid = threadIdx.x;
  if (blk < 1024) {
    gemm_body<0>(xn, WtQ, bq, qb, blk & 255, blk >> 8, tid);
    return;
  }
  const int w = tid >> 6, l = tid & 63;
  const int col = l & 15, quad = l >> 4;
  const int row0 = (blk - 1024) * 64 + w * 16;
  f32x4 acc[16];
  #pragma unroll
  for (int n = 0; n < 16; ++n) acc[n] = (f32x4){0.f, 0.f, 0.f, 0.f};
  const __bf16* ap = xp + (size_t)(row0 + col) * 256 + quad * 8;
  #pragma unroll
  for (int ks = 0; ks < 8; ++ks) {
    bf16x8 af = *(const bf16x8*)(ap + ks * 32);
    #pragma unroll
    for (int n = 0; n < 16; ++n) {
      bf16x8 bf = *(const bf16x8*)(WtM + (size_t)(n * 16 + col) * 256 + ks * 32 + quad * 8);
      acc[n] = __builtin_amdgcn_mfma_f32_16x16x32_bf16(af, bf, acc[n], 0, 0, 0);
    }
  }
  #pragma unroll
  for (int r = 0; r < 4; ++r) {
    float s = 0.f;
    #pragma unroll
    for (int n = 0; n < 16; ++n) s += acc[n][r];
    #pragma unroll
    for (int m = 1; m < 16; m <<= 1) s += __shfl_xor(s, m);
    float mean = s * (1.0f / 256.0f);
    float vs = 0.f;
    #pragma unroll
    for (int n = 0; n < 16; ++n) { float d = acc[n][r] - mean; vs += d * d; }
    #pragma unroll
    for (int m = 1; m < 16; m <<= 1) vs += __shfl_xor(vs, m);
    float rstd = rsqrtf(vs * (1.0f / 256.0f) + 1e-5f);
    int row = row0 + quad * 4 + r;
    #pragma unroll
    for (int n = 0; n < 16; ++n) {
      int cc = n * 16 + col;
      xr[(size_t)row * 256 + cc] = (__bf16)((acc[n][r] - mean) * rstd * g2[cc] + b2[cc]);
    }
  }
}

// ================= L3 "kv": K-GEMM (mode0) + V-GEMM (mode1) ==================
__global__ __launch_bounds__(256) void kv_kernel(
    const __bf16* __restrict__ xr, const __bf16* __restrict__ WtK,
    const float* __restrict__ bk, __bf16* __restrict__ kbuf,
    const __bf16* __restrict__ WtV, const float* __restrict__ bv,
    __bf16* __restrict__ vTb) {
  const int blk = blockIdx.x, tid = threadIdx.x;
  if (blk < 256) gemm_body<0>(xr, WtK, bk, kbuf, blk & 63, blk >> 6, tid);
  else { int k = blk - 256; gemm_body<1>(xr, WtV, bv, vTb, k & 63, k >> 6, tid); }
}

// ================= L5 "o": O-GEMM + bias + resid, fp32 out ===================
// LDS-bounce epilogue: MFMA fragment layout (lane owns 1 col x 4 rows) is
// re-tiled to row-contiguous float4 so resid loads + out stores are 256B
// contiguous per instruction (was: 16 scalar loads + 16 scalar stores/thread
// in 64B segments). sm write: 2-way bank alias (free); read: b128 2-way.
__global__ __launch_bounds__(256) void o_kernel(
    const __bf16* __restrict__ oat, const __bf16* __restrict__ WtO,
    const float* __restrict__ bo, const float* __restrict__ resid,
    float* __restrict__ out) {
  __shared__ float sm[4][16][68];
  const int tid = threadIdx.x;
  const int w = tid >> 6, l = tid & 63;
  const int col = l & 15, quad = l >> 4;
  const int row0 = blockIdx.x * 64 + w * 16;
  const int col0 = blockIdx.y * 64;
  f32x4 acc[4] = {{0.f,0.f,0.f,0.f},{0.f,0.f,0.f,0.f},{0.f,0.f,0.f,0.f},{0.f,0.f,0.f,0.f}};
  const __bf16* ap = oat + (size_t)(row0 + col) * 256 + quad * 8;
  #pragma unroll
  for (int ks = 0; ks < 8; ++ks) {
    bf16x8 af = *(const bf16x8*)(ap + ks * 32);
    #pragma unroll
    for (int n = 0; n < 4; ++n) {
      bf16x8 bf = *(const bf16x8*)(WtO + (size_t)(col0 + n * 16 + col) * 256 + ks * 32 + quad * 8);
      acc[n] = __builtin_amdgcn_mfma_f32_16x16x32_bf16(af, bf, acc[n], 0, 0, 0);
    }
  }
  // stage fragments (+bias) into per-wave LDS tile [16 rows][64 cols]
  #pragma unroll
  for (int n = 0; n < 4; ++n) {
    const float bv = bo[col0 + n * 16 + col];
    #pragma unroll
    for (int r = 0; r < 4; ++r)
      sm[w][quad * 4 + r][n * 16 + col] = acc[n][r] + bv;
  }
  // wave-internal LDS visibility: same-wave program order + lgkmcnt (no barrier)
  #pragma unroll
  for (int i = 0; i < 4; ++i) {
    int lr = i * 4 + quad;          // 0..15
    int f4 = l & 15;                // float4 index within 64-col strip
    size_t off = (size_t)(row0 + lr) * 256 + col0 + f4 * 4;
    float4 rv = *(const float4*)(resid + off);
    const float* sp = &sm[w][lr][f4 * 4];
    float4 ov;
    ov.x = sp[0] + rv.x; ov.y = sp[1] + rv.y;
    ov.z = sp[2] + rv.z; ov.w = sp[3] + rv.w;
    *(float4*)(out + off) = ov;
  }
}

// ================= L4 fused attention =======================================
// v3: two q-tiles per block (grid 128x32). Per tile: QK^T -> softmax with
// in-register normalize + NT attn store straight from regs -> PV (normalized
// P, no inv in epilogue) -> cross-wave reduce -> oat. Tile 0's 64 KiB attn
// store drains under tile 0 PV + tile 1 QK^T/softmax instead of serializing.
// No extra barrier between tiles: each wave's phase-3 Ss reads and next-tile
// phase-1 Ss writes touch only its own 256-col strip; part reuse is fenced by
// tile-1's phase barriers.
__device__ __forceinline__ int swz(int row, int c) {
  return row * 1024 + (c ^ ((row & 7) << 2));
}

__global__ __launch_bounds__(256) void attn_fused(
    const __bf16* __restrict__ q, const __bf16* __restrict__ kb,
    const __bf16* __restrict__ vT, float* __restrict__ attn,
    __bf16* __restrict__ oat) {
  __shared__ float Ss[16 * 1024];     // 64 KiB: scores then NORMALIZED probs
  __shared__ float part[64 * 32];     //  8 KiB: cross-wave PV reduce
  const int tid = threadIdx.x;
  const int w = tid >> 6, l = tid & 63;
  const int col = l & 15, quad = l >> 4;
  const int bh = blockIdx.y, b = bh >> 3, h = bh & 7;
  const __bf16* kbase = kb + ((size_t)(b * 1024 + col)) * 256 + h * 32 + quad * 8;
  const __bf16* v0p = vT + ((size_t)(b * 256 + h * 32 + col)) * 1024;
  const __bf16* v1p = v0p + 16 * 1024;

  for (int tile = 0; tile < 2; ++tile) {
    const int q0 = blockIdx.x * 32 + tile * 16;

    // Phase 1: S = SCALE * Q K^T for this wave's 256-col strip
    bf16x8 qf = *(const bf16x8*)(q + ((size_t)(b * 4096 + q0 + col)) * 256 + h * 32 + quad * 8);
    #pragma unroll 4
    for (int t = 0; t < 16; ++t) {
      int j0 = w * 256 + t * 16;
      bf16x8 kf = *(const bf16x8*)(kbase + (size_t)j0 * 256);
      f32x4 c = {0.f, 0.f, 0.f, 0.f};
      c = __builtin_amdgcn_mfma_f32_16x16x32_bf16(qf, kf, c, 0, 0, 0);
      #pragma unroll
      for (int r = 0; r < 4; ++r)
        Ss[swz(quad * 4 + r, j0 + col)] = c[r] * SCALE;
    }
    __syncthreads();

    // Phase 2: softmax rows w*4..w*4+3; normalize IN REGISTERS; write
    // normalized probs to LDS and NT-store attn straight from regs (stores
    // start here and drain under everything downstream).
    float* abase = attn + ((size_t)bh * 4096 + q0) * 1024;
    #pragma unroll
    for (int rr = 0; rr < 4; ++rr) {
      int row = w * 4 + rr;
      f32x4 v4[4];
      float m = -1e30f;
      #pragma unroll
      for (int i = 0; i < 4; ++i) {
        v4[i] = *(const f32x4*)(&Ss[swz(row, i * 256 + l * 4)]);
        m = fmaxf(m, fmaxf(fmaxf(v4[i][0], v4[i][1]), fmaxf(v4[i][2], v4[i][3])));
      }
      #pragma unroll
      for (int off = 32; off; off >>= 1) m = fmaxf(m, __shfl_down(m, off));
      m = __shfl(m, 0);
      float s = 0.f;
      #pragma unroll
      for (int i = 0; i < 4; ++i) {
        v4[i][0] = __expf(v4[i][0] - m); v4[i][1] = __expf(v4[i][1] - m);
        v4[i][2] = __expf(v4[i][2] - m); v4[i][3] = __expf(v4[i][3] - m);
        s += v4[i][0] + v4[i][1] + v4[i][2] + v4[i][3];
      }
      #pragma unroll
      for (int off = 32; off; off >>= 1) s += __shfl_down(s, off);
      float inv = 1.0f / __shfl(s, 0);
      float* arow = abase + (size_t)row * 1024;
      #pragma unroll
      for (int i = 0; i < 4; ++i) {
        v4[i][0] *= inv; v4[i][1] *= inv; v4[i][2] *= inv; v4[i][3] *= inv;
        *(f32x4*)(&Ss[swz(row, i * 256 + l * 4)]) = v4[i];
        __builtin_nontemporal_store(v4[i], (f32x4*)(arow + i * 256 + l * 4));
      }
    }
    __syncthreads();

    // Phase 3: partial PV over this wave's 256-col strip (normalized P)
    f32x4 a0 = {0.f, 0.f, 0.f, 0.f}, a1 = {0.f, 0.f, 0.f, 0.f};
    #pragma unroll 2
    for (int s8 = 0; s8 < 8; ++s8) {
      int k0 = w * 256 + s8 * 32;
      int c0 = k0 + quad * 8;
      f32x4 p0 = *(const f32x4*)(&Ss[swz(col, c0)]);
      f32x4 p1 = *(const f32x4*)(&Ss[swz(col, c0 + 4)]);
      bf16x8 af;
      af[0] = (__bf16)p0[0]; af[1] = (__bf16)p0[1]; af[2] = (__bf16)p0[2]; af[3] = (__bf16)p0[3];
      af[4] = (__bf16)p1[0]; af[5] = (__bf16)p1[1]; af[6] = (__bf16)p1[2]; af[7] = (__bf16)p1[3];
      bf16x8 b0 = *(const bf16x8*)(v0p + k0 + quad * 8);
      bf16x8 b1 = *(const bf16x8*)(v1p + k0 + quad * 8);
      a0 = __builtin_amdgcn_mfma_f32_16x16x32_bf16(af, b0, a0, 0, 0, 0);
      a1 = __builtin_amdgcn_mfma_f32_16x16x32_bf16(af, b1, a1, 0, 0, 0);
    }

    // cross-wave reduce via separate part buffer
    #pragma unroll
    for (int r = 0; r < 4; ++r) {
      part[(w * 16 + quad * 4 + r) * 32 + col] = a0[r];
      part[(w * 16 + quad * 4 + r) * 32 + 16 + col] = a1[r];
    }
    __syncthreads();
    int idx = tid;
    #pragma unroll
    for (int it = 0; it < 2; ++it, idx += 256) {
      int row = idx >> 5, d = idx & 31;
      float sum = part[row * 32 + d] + part[(16 + row) * 32 + d]
                + part[(32 + row) * 32 + d] + part[(48 + row) * 32 + d];
      oat[((size_t)(b * 4096 + q0 + row)) * 256 + h * 32 + d] = (__bf16)sum;
    }
    // next tile: wave-local Ss strip rewrite needs no barrier; part writes
    // are fenced by the next tile's phase-1/2 barriers.
  }
}

extern "C" void kernel_launch(void* const* d_in, const int* in_sizes, int n_in,
                              void* d_out, int out_size, void* d_ws, size_t ws_size,
                              hipStream_t stream) {
  (void)in_sizes; (void)n_in; (void)out_size; (void)ws_size;
  const float* x     = (const float*)d_in[0];
  const float* ln1_g = (const float*)d_in[2];
  const float* ln1_b = (const float*)d_in[3];
  const float* Wq    = (const float*)d_in[4];
  const float* bq    = (const float*)d_in[5];
  const float* Wk    = (const float*)d_in[6];
  const float* bk    = (const float*)d_in[7];
  const float* Wv    = (const float*)d_in[8];
  const float* bv    = (const float*)d_in[9];
  const float* Wmean = (const float*)d_in[10];
  const float* ln2_g = (const float*)d_in[11];
  const float* ln2_b = (const float*)d_in[12];
  const float* Wo    = (const float*)d_in[13];
  const float* bo    = (const float*)d_in[14];

  float* out  = (float*)d_out;           // [16384, 256] fp32
  float* attn = out + 4194304;           // [32, 4096, 1024] fp32

  __bf16* w0   = (__bf16*)d_ws;
  __bf16* xn   = w0;                     // 4,194,304
  __bf16* qb   = w0 + 4194304;           // 4,194,304
  __bf16* oat  = w0 + 8388608;           // 4,194,304
  __bf16* xp   = w0 + 12582912;          // 1,048,576
  __bf16* xr   = w0 + 14680064;          // 1,048,576
  __bf16* kbuf = w0 + 15728640;          // 1,048,576
  __bf16* vTb  = w0 + 16777216;          // 1,048,576
  __bf16* WtQ  = w0 + 17825792;          // 5 x 65,536
  __bf16* WtK  = WtQ + 65536;
  __bf16* WtV  = WtK + 65536;
  __bf16* WtM  = WtV + 65536;
  __bf16* WtO  = WtM + 65536;

  // L1: castw(1280) + LN1(4096) + pool(1024) = 6400 blocks
  prep_kernel<<<6400, 256, 0, stream>>>(Wq, Wk, Wv, Wmean, Wo,
                                        WtQ, WtK, WtV, WtM, WtO,
                                        x, ln1_g, ln1_b, xn, xp);
  // L2: Q-GEMM(1024) + meanGEMM+LN2(64) = 1088 blocks
  qm_kernel<<<1088, 256, 0, stream>>>(xn, WtQ, bq, qb, xp, WtM, ln2_g, ln2_b, xr);
  // L3: K-GEMM(256) + V-GEMM(256) = 512 blocks
  kv_kernel<<<512, 256, 0, stream>>>(xr, WtK, bk, kbuf, WtV, bv, vTb);
  // L4: fused attention, 2 q-tiles per block
  attn_fused<<<dim3(128, 32), 256, 0, stream>>>(qb, kbuf, vTb, attn, oat);
  // L5: O-GEMM + bias + residual (LDS-bounce float4 epilogue)
  o_kernel<<<dim3(256, 4), 256, 0, stream>>>(oat, WtO, bo, x, out);
}